// Round 4
// baseline (362.440 us; speedup 1.0000x reference)
//
#include <hip/hip_runtime.h>
#include <hip/hip_bf16.h>
#include <math.h>

#define B_ 1024
#define M_ 16384
#define D_ 512
#define C_ 100
#define L_ 50

using short8  = __attribute__((ext_vector_type(8))) short;
using ushort8 = __attribute__((ext_vector_type(8))) unsigned short;
using f32x4   = __attribute__((ext_vector_type(4))) float;

__device__ inline void async16(const void* g, void* l) {
    __builtin_amdgcn_global_load_lds(
        (const __attribute__((address_space(1))) unsigned int*)g,
        (__attribute__((address_space(3))) unsigned int*)l, 16, 0, 0);
}

// ---------------- K_pre: class counts + scores + posAcc/acc zero ----------------
// blocks [0,C_): cnt_buf[c] = #buffer elems with label c
// blocks [C_,C_+B_/4): scores = sigmoid(F@W+b) (4 rows/block), posAcc zero; block C_ zeroes acc
__global__ __launch_bounds__(256) void k_pre(
    const int* __restrict__ blab, const float* __restrict__ F,
    const float* __restrict__ W, const float* __restrict__ bbias,
    int* __restrict__ cnt_buf, float* __restrict__ scores,
    float* __restrict__ posAcc, float* __restrict__ acc) {
    int b = blockIdx.x, t = threadIdx.x;
    if (b < C_) {
        int c = 0;
#pragma unroll
        for (int q = 0; q < 8; q++) {
            int base = q * 2048 + t * 8;
            int4 l0 = *(const int4*)(blab + base);
            int4 l1 = *(const int4*)(blab + base + 4);
            c += (l0.x == b) + (l0.y == b) + (l0.z == b) + (l0.w == b)
               + (l1.x == b) + (l1.y == b) + (l1.z == b) + (l1.w == b);
        }
#pragma unroll
        for (int o = 32; o; o >>= 1) c += __shfl_xor(c, o);
        __shared__ int w4[4];
        if ((t & 63) == 0) w4[t >> 6] = c;
        __syncthreads();
        if (t == 0) cnt_buf[b] = w4[0] + w4[1] + w4[2] + w4[3];
    } else {
        int bb2 = b - C_;
        if (bb2 == 0 && t < 8) acc[t] = 0.f;
        int wave = t >> 6, lane = t & 63;
        int row = bb2 * 4 + wave;
        const float* p = F + (size_t)row * D_;
        float s = 0.f;
        for (int e = lane; e < D_; e += 64) s += p[e] * W[e];
#pragma unroll
        for (int off = 32; off > 0; off >>= 1) s += __shfl_down(s, off);
        if (lane == 0) {
            scores[row] = 1.f / (1.f + __expf(-(s + bbias[0])));
            posAcc[row] = 0.f;
        }
    }
}

// ---------------- K1: norms + normalized bf16 conversion ----------------
__global__ __launch_bounds__(256) void k_prep(
    const float* __restrict__ feat, const float* __restrict__ buf,
    const float* __restrict__ protos, const float* __restrict__ oldp,
    const int* __restrict__ lc,
    __hip_bfloat16* __restrict__ fbf, __hip_bfloat16* __restrict__ bbf,
    float* __restrict__ inv_feat, float* __restrict__ inv_np,
    float* __restrict__ inv_op) {
    int b = blockIdx.x, t = threadIdx.x;
    const float* src; int row;
    __hip_bfloat16* dst = nullptr; float* ndst = nullptr;
    if (b < B_)                { src = feat;   row = b;                 dst = fbf + (size_t)b * D_; ndst = &inv_feat[b]; }
    else if (b < B_ + M_)      { int j = b - B_;           src = buf;    row = j;     dst = bbf + (size_t)j * D_; }
    else if (b < B_ + M_ + L_) { int j = b - B_ - M_;      src = protos; row = lc[j]; ndst = &inv_np[j]; }
    else                       { int j = b - B_ - M_ - L_; src = oldp;   row = lc[j]; ndst = &inv_op[j]; }
    const float* p = src + (size_t)row * D_;
    float v0 = p[t], v1 = p[t + 256];
    float ss = v0 * v0 + v1 * v1;
#pragma unroll
    for (int m = 32; m; m >>= 1) ss += __shfl_xor(ss, m);
    __shared__ float w4[4];
    if ((t & 63) == 0) w4[t >> 6] = ss;
    __syncthreads();
    float inv = 1.f / fmaxf(sqrtf(w4[0] + w4[1] + w4[2] + w4[3]), 1e-12f);
    if (dst) { dst[t] = __float2bfloat16(v0 * inv); dst[t + 256] = __float2bfloat16(v1 * inv); }
    if (ndst && t == 0) *ndst = inv;
}

// ---------------- K2: bf16 MFMA GEMM -> 16-bit sort keys + pos_exp atomics ----
// key(bf16 bits of clipped sim) monotone ascending; positives -> key=0 and
// contribute e^{bf16val} to posAcc[row] via global atomicAdd (rare: ~160/row).
#define TM 128
#define TN 128
#define TK 32
__global__ __launch_bounds__(256) void k_gemm(
    const __hip_bfloat16* __restrict__ A, const __hip_bfloat16* __restrict__ Bm,
    const int* __restrict__ labels, const int* __restrict__ blab,
    unsigned short* __restrict__ keys, float* __restrict__ posAcc) {
    __shared__ unsigned short As[TM * TK];
    __shared__ unsigned short Bs[TN * TK];
    int t = threadIdx.x;
    int wave = t >> 6, lane = t & 63;
    int row0 = blockIdx.y * TM;
    int col0 = blockIdx.x * TN;
    int c0 = t, c1 = t + 256;
    const ushort* Ag0 = (const ushort*)A + (size_t)(row0 + (c0 >> 2)) * D_ + (c0 & 3) * 8;
    const ushort* Ag1 = (const ushort*)A + (size_t)(row0 + (c1 >> 2)) * D_ + (c1 & 3) * 8;
    const ushort* Bg0 = (const ushort*)Bm + (size_t)(col0 + (c0 >> 2)) * D_ + (c0 & 3) * 8;
    const ushort* Bg1 = (const ushort*)Bm + (size_t)(col0 + (c1 >> 2)) * D_ + (c1 & 3) * 8;
    unsigned short* As0 = &As[c0 * 8]; unsigned short* As1 = &As[c1 * 8];
    unsigned short* Bs0 = &Bs[c0 * 8]; unsigned short* Bs1 = &Bs[c1 * 8];
    int wm = (wave & 1) * 64, wn = (wave >> 1) * 64;
    f32x4 acc[4][4];
#pragma unroll
    for (int i = 0; i < 4; i++)
#pragma unroll
        for (int j = 0; j < 4; j++) acc[i][j] = {0.f, 0.f, 0.f, 0.f};
    int fr = lane & 15, fk = (lane >> 4) * 8;
    for (int k0 = 0; k0 < D_; k0 += TK) {
        async16(Ag0 + k0, As0);
        async16(Ag1 + k0, As1);
        async16(Bg0 + k0, Bs0);
        async16(Bg1 + k0, Bs1);
        __syncthreads();
        short8 af[4], bf2[4];
#pragma unroll
        for (int i = 0; i < 4; i++)
            af[i] = *(const short8*)&As[(wm + i * 16 + fr) * TK + fk];
#pragma unroll
        for (int j = 0; j < 4; j++)
            bf2[j] = *(const short8*)&Bs[(wn + j * 16 + fr) * TK + fk];
#pragma unroll
        for (int i = 0; i < 4; i++)
#pragma unroll
            for (int j = 0; j < 4; j++)
                acc[i][j] = __builtin_amdgcn_mfma_f32_16x16x32_bf16(af[i], bf2[j], acc[i][j], 0, 0, 0);
        __syncthreads();
    }
    int quad = lane >> 4, cpos = lane & 15;
#pragma unroll
    for (int j = 0; j < 4; j++) {
        int gc = col0 + wn + j * 16 + cpos;
        int bl = blab[gc];
#pragma unroll
        for (int i = 0; i < 4; i++) {
            int gr0 = row0 + wm + i * 16 + quad * 4;
#pragma unroll
            for (int r = 0; r < 4; r++) {
                int gr = gr0 + r;
                float v = fminf(fmaxf(acc[i][j][r] * 5.0f, -10.f), 10.f);
                // RNE bf16 round (matches __float2bfloat16 for normal values)
                unsigned u = __float_as_uint(v);
                unsigned bits = (u + 0x7FFFu + ((u >> 16) & 1u)) >> 16;
                unsigned key = (bits & 0x8000u) ? (~bits & 0xFFFFu) : (bits | 0x8000u);
                if (bl == labels[gr]) {
                    atomicAdd(&posAcc[gr], __expf(__uint_as_float(bits << 16)));
                    key = 0u;
                }
                keys[(size_t)gr * M_ + gc] = (unsigned short)key;
            }
        }
    }
}

// ---------------- K3: per-row exact top-k via bisection on packed keys ----------
// keys held as 32 packed u32 VGPRs (2 x 16-bit) -> cannot spill.
// T* = max T with count(key>=T) >= k; neg_exp = sum_{key>T*} e^s + (k-cnt_gt)*e^{val(T*)}.
__global__ __launch_bounds__(256) void k_select(
    const unsigned short* __restrict__ keys, const int* __restrict__ labels,
    const float* __restrict__ posAcc, const int* __restrict__ cnt_buf,
    float* __restrict__ acc) {
    int row = blockIdx.x;
    int t = threadIdx.x;
    int wave = t >> 6;
    const unsigned short* kr = keys + (size_t)row * M_;

    unsigned kp[32];
#pragma unroll
    for (int q = 0; q < 8; q++) {
        uint4 v = *(const uint4*)(kr + q * 2048 + t * 8);
        kp[q * 4 + 0] = v.x; kp[q * 4 + 1] = v.y; kp[q * 4 + 2] = v.z; kp[q * 4 + 3] = v.w;
    }

    int lab = labels[row];
    int n_pos = cnt_buf[lab];
    int k = (int)(0.7f * (float)(M_ - n_pos));   // fp32-mul + trunc matches reference

    __shared__ int warr[16][4];
    unsigned cur = 0;
    for (int r = 15; r >= 0; r--) {
        int T = (int)(cur | (1u << r));
        int neg = 0;  // accumulates -(count of keys < T); branchless, no vcc chains
#pragma unroll
        for (int q = 0; q < 32; q++) {
            neg += ((int)(kp[q] & 0xFFFFu) - T) >> 31;
            neg += ((int)(kp[q] >> 16) - T) >> 31;
        }
        int cnt = 64 + neg;
#pragma unroll
        for (int o = 32; o; o >>= 1) cnt += __shfl_xor(cnt, o);
        if ((t & 63) == 0) warr[15 - r][wave] = cnt;
        __syncthreads();
        int tot = warr[15 - r][0] + warr[15 - r][1] + warr[15 - r][2] + warr[15 - r][3];
        if (tot >= k) cur = (unsigned)T;
    }

    // final pass: strict > T*
    int cgt = 0; float sgt = 0.f;
#pragma unroll
    for (int q = 0; q < 32; q++) {
#pragma unroll
        for (int h = 0; h < 2; h++) {
            unsigned key = h ? (kp[q] >> 16) : (kp[q] & 0xFFFFu);
            if (key > cur) {
                cgt++;
                unsigned bits = (key & 0x8000u) ? (key ^ 0x8000u) : (~key & 0xFFFFu);
                sgt += __expf(__uint_as_float(bits << 16));
            }
        }
    }
#pragma unroll
    for (int o = 32; o; o >>= 1) {
        sgt += __shfl_xor(sgt, o);
        cgt += __shfl_xor(cgt, o);
    }
    __shared__ float rS[4]; __shared__ int rC[4];
    if ((t & 63) == 0) { rS[wave] = sgt; rC[wave] = cgt; }
    __syncthreads();
    if (t == 0) {
        float sumGt = rS[0] + rS[1] + rS[2] + rS[3];
        int   cntGt = rC[0] + rC[1] + rC[2] + rC[3];
        float negExp = 0.f;
        if (k > 0) {
            unsigned bits = (cur & 0x8000u) ? (cur ^ 0x8000u) : (~cur & 0xFFFFu);
            float tval = __expf(__uint_as_float(bits << 16));
            negExp = sumGt + (float)(k - cntGt) * tval;
        }
        float pos_exp = posAcc[row] / (float)max(n_pos, 1);
        int valid = (k > 0 && n_pos > 0) ? 1 : 0;
        float denom = fmaxf(pos_exp + negExp, 1e-8f);
        float ratio = fminf(fmaxf(pos_exp / denom, 1e-8f), 1.0f);
        float loss = fminf(fmaxf(-logf(ratio), 0.f), 5.f);
        if (valid) { atomicAdd(&acc[0], loss); atomicAdd(&acc[1], 1.f); }
    }
}

// ---------------- K5: per-class boundary stats ----------------
__global__ __launch_bounds__(256) void k_class(
    const float* __restrict__ F, const int* __restrict__ labels,
    const float* __restrict__ scores, float* __restrict__ acc) {
    int c = blockIdx.x;
    int t = threadIdx.x;
    __shared__ int slab[B_];
    for (int r = t; r < B_; r += 256) slab[r] = labels[r];
    __shared__ float ssum; __shared__ int scnt;
    if (t == 0) { ssum = 0.f; scnt = 0; }
    __syncthreads();
    float s0 = 0.f, s1 = 0.f, q0 = 0.f, q1 = 0.f;
    float local_s = 0.f; int local_n = 0;
    for (int r = 0; r < B_; r++) {
        if (slab[r] == c) {
            const float* p = F + (size_t)r * D_;
            float v0 = p[t], v1 = p[t + 256];
            s0 += v0; s1 += v1; q0 += v0 * v0; q1 += v1 * v1;
            if (t == 0) { local_s += scores[r]; local_n++; }
        }
    }
    if (t == 0) { ssum = local_s; scnt = local_n; }
    __syncthreads();
    float fn = (float)scnt;
    float safe_n = fmaxf(fn, 1.f);
    float m0 = s0 / safe_n, m1 = s1 / safe_n;
    float dv = fmaxf(fn - 1.f, 1.f);
    float v0 = (q0 - fn * m0 * m0) / dv;
    float v1 = (q1 - fn * m1 * m1) / dv;
    __shared__ float red[256];
    red[t] = v0 + v1;
    __syncthreads();
    for (int s = 128; s > 0; s >>= 1) { if (t < s) red[t] += red[t + s]; __syncthreads(); }
    if (t == 0) {
        float var_mean = red[0] / 512.f;
        var_mean = fminf(fmaxf(var_mean, 1e-6f), 100.f);
        float target = 1.f / (1.f + expf(-var_mean));
        float mean_s = ssum / safe_n;
        float d = mean_s - target;
        float bl = fminf(d * d, 2.f);
        if (fn > 1.f) { atomicAdd(&acc[2], bl); atomicAdd(&acc[3], 1.f); }
    }
}

// ---------------- K6: PRD KL per row ----------------
__global__ __launch_bounds__(256) void k_prd(
    const float* __restrict__ F, const float* __restrict__ protos,
    const float* __restrict__ oldp, const int* __restrict__ lc,
    const float* __restrict__ inv_f, const float* __restrict__ inv_np,
    const float* __restrict__ inv_op, float* __restrict__ acc) {
    int row = blockIdx.x;
    int t = threadIdx.x;
    __shared__ float f[D_];
    __shared__ float so[L_], sn[L_];
    float invf = inv_f[row] * 5.0f;
    const float* p = F + (size_t)row * D_;
    f[t] = p[t]; f[t + 256] = p[t + 256];
    __syncthreads();
    int wave = t >> 6, lane = t & 63;
    for (int j = wave; j < 2 * L_; j += 4) {
        int idx = (j < L_) ? j : j - L_;
        const float* P = ((j < L_) ? oldp : protos) + (size_t)lc[idx] * D_;
        float inv = (j < L_) ? inv_op[idx] : inv_np[idx];
        float s = 0.f;
        for (int e = lane; e < D_; e += 64) s += f[e] * P[e];
#pragma unroll
        for (int off = 32; off > 0; off >>= 1) s += __shfl_down(s, off);
        if (lane == 0) {
            float v = fminf(fmaxf(s * invf * inv, -10.f), 10.f);
            if (j < L_) so[idx] = v; else sn[idx] = v;
        }
    }
    __syncthreads();
    if (t == 0) {
        float mo = -1e30f, mn = -1e30f;
        for (int i = 0; i < L_; i++) { mo = fmaxf(mo, so[i]); mn = fmaxf(mn, sn[i]); }
        float eo = 0.f, en = 0.f;
        for (int i = 0; i < L_; i++) { eo += __expf(so[i] - mo); en += __expf(sn[i] - mn); }
        float lo = logf(eo), ln_ = logf(en);
        float kl = 0.f;
        for (int i = 0; i < L_; i++) {
            float olp = so[i] - mo - lo;
            float nlp = sn[i] - mn - ln_;
            kl += __expf(olp) * (olp - nlp);
        }
        atomicAdd(&acc[4], kl);
    }
}

// ---------------- K7: combine ----------------
__global__ void k_final(const float* __restrict__ acc, float* __restrict__ out) {
    float hard = acc[0] / fmaxf(acc[1], 1.f);
    float boundary = acc[2] / fmaxf(acc[3], 1.f);
    float kl = fminf(fmaxf(acc[4] / (float)B_, 0.f), 5.f);
    out[0] = hard + 0.1f * boundary + 0.2f * kl;
}

extern "C" void kernel_launch(void* const* d_in, const int* in_sizes, int n_in,
                              void* d_out, int out_size, void* d_ws, size_t ws_size,
                              hipStream_t stream) {
    const float* feat   = (const float*)d_in[0];
    const float* buf    = (const float*)d_in[1];
    const float* protos = (const float*)d_in[2];
    const float* oldp   = (const float*)d_in[3];
    const float* W      = (const float*)d_in[4];
    const float* bb     = (const float*)d_in[5];
    const int* labels   = (const int*)d_in[6];
    const int* blab     = (const int*)d_in[7];
    const int* lc       = (const int*)d_in[8];
    float* out = (float*)d_out;

    char* wsb = (char*)d_ws;
    unsigned short* keyb = (unsigned short*)wsb;                 // 32 MiB
    __hip_bfloat16* fbf  = (__hip_bfloat16*)(wsb + 33554432);    // 1 MiB
    __hip_bfloat16* bbf  = (__hip_bfloat16*)(wsb + 34603008);    // 16 MiB
    float* inv_feat = (float*)(wsb + 51380224);
    float* inv_np   = inv_feat + B_;
    float* inv_op   = inv_np + L_;
    float* scores   = inv_op + L_;
    float* posAcc   = scores + B_;
    int*   cnt_buf  = (int*)(posAcc + B_);
    float* acc      = (float*)(cnt_buf + 128);

    k_pre<<<C_ + B_ / 4, 256, 0, stream>>>(blab, feat, W, bb, cnt_buf, scores, posAcc, acc);
    k_prep<<<B_ + M_ + 2 * L_, 256, 0, stream>>>(feat, buf, protos, oldp, lc,
                                                 fbf, bbf, inv_feat, inv_np, inv_op);
    dim3 g(M_ / TN, B_ / TM);
    k_gemm<<<g, 256, 0, stream>>>(fbf, bbf, labels, blab, keyb, posAcc);
    k_select<<<B_, 256, 0, stream>>>(keyb, labels, posAcc, cnt_buf, acc);
    k_class<<<C_, 256, 0, stream>>>(feat, labels, scores, acc);
    k_prd<<<B_, 256, 0, stream>>>(feat, protos, oldp, lc, inv_feat, inv_np, inv_op, acc);
    k_final<<<1, 1, 0, stream>>>(acc, out);
}

// Round 5
// 268.910 us; speedup vs baseline: 1.3478x; 1.3478x over previous
//
#include <hip/hip_runtime.h>
#include <hip/hip_bf16.h>
#include <math.h>

#define B_ 1024
#define M_ 16384
#define D_ 512
#define C_ 100
#define L_ 50

using short8  = __attribute__((ext_vector_type(8))) short;
using ushort8 = __attribute__((ext_vector_type(8))) unsigned short;
using f32x4   = __attribute__((ext_vector_type(4))) float;

__device__ inline void async16(const void* g, void* l) {
    __builtin_amdgcn_global_load_lds(
        (const __attribute__((address_space(1))) unsigned int*)g,
        (__attribute__((address_space(3))) unsigned int*)l, 16, 0, 0);
}

// ---------------- K_pre: class bitmasks + counts + scores + acc zero ----------------
// blocks [0,C_): maskT[c][t] (byte q = pos-bits for elems q*2048+t*8..+7) + cnt_buf[c]
// blocks [C_,C_+B_/4): scores = sigmoid(F@W+b) (4 rows/block); block C_ zeroes acc
__global__ __launch_bounds__(256) void k_pre(
    const int* __restrict__ blab, const float* __restrict__ F,
    const float* __restrict__ W, const float* __restrict__ bbias,
    unsigned long long* __restrict__ maskT, int* __restrict__ cnt_buf,
    float* __restrict__ scores, float* __restrict__ acc) {
    int b = blockIdx.x, t = threadIdx.x;
    if (b < C_) {
        unsigned long long m = 0;
#pragma unroll
        for (int q = 0; q < 8; q++) {
            int base = q * 2048 + t * 8;
            int4 l0 = *(const int4*)(blab + base);
            int4 l1 = *(const int4*)(blab + base + 4);
            unsigned by = 0;
            by |= (unsigned)(l0.x == b) << 0; by |= (unsigned)(l0.y == b) << 1;
            by |= (unsigned)(l0.z == b) << 2; by |= (unsigned)(l0.w == b) << 3;
            by |= (unsigned)(l1.x == b) << 4; by |= (unsigned)(l1.y == b) << 5;
            by |= (unsigned)(l1.z == b) << 6; by |= (unsigned)(l1.w == b) << 7;
            m |= ((unsigned long long)by) << (8 * q);
        }
        maskT[(size_t)b * 256 + t] = m;
        int c = __popcll(m);
#pragma unroll
        for (int o = 32; o; o >>= 1) c += __shfl_xor(c, o);
        __shared__ int w4[4];
        if ((t & 63) == 0) w4[t >> 6] = c;
        __syncthreads();
        if (t == 0) cnt_buf[b] = w4[0] + w4[1] + w4[2] + w4[3];
    } else {
        int bb2 = b - C_;
        if (bb2 == 0 && t < 8) acc[t] = 0.f;
        int wave = t >> 6, lane = t & 63;
        int row = bb2 * 4 + wave;
        const float* p = F + (size_t)row * D_;
        float s = 0.f;
        for (int e = lane; e < D_; e += 64) s += p[e] * W[e];
#pragma unroll
        for (int off = 32; off > 0; off >>= 1) s += __shfl_down(s, off);
        if (lane == 0) scores[row] = 1.f / (1.f + __expf(-(s + bbias[0])));
    }
}

// ---------------- K1: norms + normalized bf16 conversion ----------------
__global__ __launch_bounds__(256) void k_prep(
    const float* __restrict__ feat, const float* __restrict__ buf,
    const float* __restrict__ protos, const float* __restrict__ oldp,
    const int* __restrict__ lc,
    __hip_bfloat16* __restrict__ fbf, __hip_bfloat16* __restrict__ bbf,
    float* __restrict__ inv_feat, float* __restrict__ inv_np,
    float* __restrict__ inv_op) {
    int b = blockIdx.x, t = threadIdx.x;
    const float* src; int row;
    __hip_bfloat16* dst = nullptr; float* ndst = nullptr;
    if (b < B_)                { src = feat;   row = b;                 dst = fbf + (size_t)b * D_; ndst = &inv_feat[b]; }
    else if (b < B_ + M_)      { int j = b - B_;           src = buf;    row = j;     dst = bbf + (size_t)j * D_; }
    else if (b < B_ + M_ + L_) { int j = b - B_ - M_;      src = protos; row = lc[j]; ndst = &inv_np[j]; }
    else                       { int j = b - B_ - M_ - L_; src = oldp;   row = lc[j]; ndst = &inv_op[j]; }
    const float* p = src + (size_t)row * D_;
    float v0 = p[t], v1 = p[t + 256];
    float ss = v0 * v0 + v1 * v1;
#pragma unroll
    for (int m = 32; m; m >>= 1) ss += __shfl_xor(ss, m);
    __shared__ float w4[4];
    if ((t & 63) == 0) w4[t >> 6] = ss;
    __syncthreads();
    float inv = 1.f / fmaxf(sqrtf(w4[0] + w4[1] + w4[2] + w4[3]), 1e-12f);
    if (dst) { dst[t] = __float2bfloat16(v0 * inv); dst[t + 256] = __float2bfloat16(v1 * inv); }
    if (ndst && t == 0) *ndst = inv;
}

// ---------------- K2: bf16 MFMA GEMM -> 16-bit sort keys (coalesced stores) ----
// key monotone ascending in sim value; positives NOT handled here (k_select masks).
#define TM 128
#define TN 128
#define TK 32
#define CPITCH 136   // ushorts; 272 B = 16B-aligned pitch for dwordx4 LDS reads
__global__ __launch_bounds__(256) void k_gemm(
    const __hip_bfloat16* __restrict__ A, const __hip_bfloat16* __restrict__ Bm,
    unsigned short* __restrict__ keys) {
    __shared__ unsigned short smem[TM * CPITCH];   // 34.8 KB; K-loop uses first 16 KB
    unsigned short* As = smem;             // TM*TK = 4096
    unsigned short* Bs = smem + TM * TK;   // 4096
    int t = threadIdx.x;
    int wave = t >> 6, lane = t & 63;
    int row0 = blockIdx.y * TM;
    int col0 = blockIdx.x * TN;
    int c0 = t, c1 = t + 256;
    const ushort* Ag0 = (const ushort*)A + (size_t)(row0 + (c0 >> 2)) * D_ + (c0 & 3) * 8;
    const ushort* Ag1 = (const ushort*)A + (size_t)(row0 + (c1 >> 2)) * D_ + (c1 & 3) * 8;
    const ushort* Bg0 = (const ushort*)Bm + (size_t)(col0 + (c0 >> 2)) * D_ + (c0 & 3) * 8;
    const ushort* Bg1 = (const ushort*)Bm + (size_t)(col0 + (c1 >> 2)) * D_ + (c1 & 3) * 8;
    unsigned short* As0 = &As[c0 * 8]; unsigned short* As1 = &As[c1 * 8];
    unsigned short* Bs0 = &Bs[c0 * 8]; unsigned short* Bs1 = &Bs[c1 * 8];
    int wm = (wave & 1) * 64, wn = (wave >> 1) * 64;
    f32x4 acc[4][4];
#pragma unroll
    for (int i = 0; i < 4; i++)
#pragma unroll
        for (int j = 0; j < 4; j++) acc[i][j] = {0.f, 0.f, 0.f, 0.f};
    int fr = lane & 15, fk = (lane >> 4) * 8;
    for (int k0 = 0; k0 < D_; k0 += TK) {
        async16(Ag0 + k0, As0);
        async16(Ag1 + k0, As1);
        async16(Bg0 + k0, Bs0);
        async16(Bg1 + k0, Bs1);
        __syncthreads();
        short8 af[4], bf2[4];
#pragma unroll
        for (int i = 0; i < 4; i++)
            af[i] = *(const short8*)&As[(wm + i * 16 + fr) * TK + fk];
#pragma unroll
        for (int j = 0; j < 4; j++)
            bf2[j] = *(const short8*)&Bs[(wn + j * 16 + fr) * TK + fk];
#pragma unroll
        for (int i = 0; i < 4; i++)
#pragma unroll
            for (int j = 0; j < 4; j++)
                acc[i][j] = __builtin_amdgcn_mfma_f32_16x16x32_bf16(af[i], bf2[j], acc[i][j], 0, 0, 0);
        __syncthreads();
    }
    // epilogue: clip -> RNE bf16 -> monotone key -> LDS transpose -> dwordx4 stores
    int quad = lane >> 4, cpos = lane & 15;
#pragma unroll
    for (int i = 0; i < 4; i++)
#pragma unroll
        for (int j = 0; j < 4; j++)
#pragma unroll
            for (int r = 0; r < 4; r++) {
                int lr2 = wm + i * 16 + quad * 4 + r;
                int lc2 = wn + j * 16 + cpos;
                float v = fminf(fmaxf(acc[i][j][r] * 5.0f, -10.f), 10.f);
                unsigned u = __float_as_uint(v);
                unsigned bits = (u + 0x7FFFu + ((u >> 16) & 1u)) >> 16;   // RNE bf16
                unsigned key = (bits & 0x8000u) ? (~bits & 0xFFFFu) : (bits | 0x8000u);
                smem[lr2 * CPITCH + lc2] = (unsigned short)key;
            }
    __syncthreads();
    int lr3 = t >> 4, lc3 = (t & 15) * 8;
#pragma unroll
    for (int p = 0; p < 8; p++) {
        int row = p * 16 + lr3;
        uint4 kv = *(const uint4*)&smem[row * CPITCH + lc3];
        *(uint4*)&keys[(size_t)(row0 + row) * M_ + col0 + lc3] = kv;
    }
}

// ---------------- K3: per-row exact top-k via bisection on packed keys ----------
// keys in 32 packed u32 VGPRs (2 x 16-bit) -> no spill. Positives zeroed via maskT;
// pos_exp accumulated from their reconstructed bf16 values (rare branch).
__global__ __launch_bounds__(256) void k_select(
    const unsigned short* __restrict__ keys, const int* __restrict__ labels,
    const unsigned long long* __restrict__ maskT, const int* __restrict__ cnt_buf,
    float* __restrict__ acc) {
    int row = blockIdx.x;
    int t = threadIdx.x;
    int wave = t >> 6;
    int lab = labels[row];
    unsigned long long pm = maskT[(size_t)lab * 256 + t];
    const unsigned short* kr = keys + (size_t)row * M_ + t * 8;

    unsigned kp[32];
    float pp = 0.f;
#pragma unroll
    for (int q = 0; q < 8; q++) {
        uint4 v = *(const uint4*)(kr + q * 2048);
        unsigned pb = (unsigned)(pm >> (8 * q)) & 0xFFu;
        unsigned w[4] = {v.x, v.y, v.z, v.w};
        if (pb) {
#pragma unroll
            for (int h = 0; h < 4; h++) {
                if (pb & (1u << (2 * h))) {
                    unsigned key = w[h] & 0xFFFFu;
                    unsigned bits = (key & 0x8000u) ? (key ^ 0x8000u) : (~key & 0xFFFFu);
                    pp += __expf(__uint_as_float(bits << 16));
                    w[h] &= 0xFFFF0000u;
                }
                if (pb & (2u << (2 * h))) {
                    unsigned key = w[h] >> 16;
                    unsigned bits = (key & 0x8000u) ? (key ^ 0x8000u) : (~key & 0xFFFFu);
                    pp += __expf(__uint_as_float(bits << 16));
                    w[h] &= 0x0000FFFFu;
                }
            }
        }
        kp[q * 4 + 0] = w[0]; kp[q * 4 + 1] = w[1];
        kp[q * 4 + 2] = w[2]; kp[q * 4 + 3] = w[3];
    }

    int n_pos = cnt_buf[lab];
    int k = (int)(0.7f * (float)(M_ - n_pos));   // fp32-mul + trunc matches reference

    __shared__ int warr[16][4];
    unsigned cur = 0;
    for (int r = 15; r >= 0; r--) {
        int T = (int)(cur | (1u << r));
        int neg = 0;  // -(count of keys < T), branchless
#pragma unroll
        for (int q = 0; q < 32; q++) {
            neg += ((int)(kp[q] & 0xFFFFu) - T) >> 31;
            neg += ((int)(kp[q] >> 16) - T) >> 31;
        }
        int cnt = 64 + neg;
#pragma unroll
        for (int o = 32; o; o >>= 1) cnt += __shfl_xor(cnt, o);
        if ((t & 63) == 0) warr[15 - r][wave] = cnt;
        __syncthreads();
        int tot = warr[15 - r][0] + warr[15 - r][1] + warr[15 - r][2] + warr[15 - r][3];
        if (tot >= k) cur = (unsigned)T;
    }

    // final pass: strict > T*
    int cgt = 0; float sgt = 0.f;
#pragma unroll
    for (int q = 0; q < 32; q++) {
#pragma unroll
        for (int h = 0; h < 2; h++) {
            unsigned key = h ? (kp[q] >> 16) : (kp[q] & 0xFFFFu);
            if (key > cur) {
                cgt++;
                unsigned bits = (key & 0x8000u) ? (key ^ 0x8000u) : (~key & 0xFFFFu);
                sgt += __expf(__uint_as_float(bits << 16));
            }
        }
    }
#pragma unroll
    for (int o = 32; o; o >>= 1) {
        pp  += __shfl_xor(pp, o);
        sgt += __shfl_xor(sgt, o);
        cgt += __shfl_xor(cgt, o);
    }
    __shared__ float rP[4], rS[4]; __shared__ int rC[4];
    if ((t & 63) == 0) { rP[wave] = pp; rS[wave] = sgt; rC[wave] = cgt; }
    __syncthreads();
    if (t == 0) {
        float posAcc = rP[0] + rP[1] + rP[2] + rP[3];
        float sumGt  = rS[0] + rS[1] + rS[2] + rS[3];
        int   cntGt  = rC[0] + rC[1] + rC[2] + rC[3];
        float negExp = 0.f;
        if (k > 0) {
            unsigned bits = (cur & 0x8000u) ? (cur ^ 0x8000u) : (~cur & 0xFFFFu);
            float tval = __expf(__uint_as_float(bits << 16));
            negExp = sumGt + (float)(k - cntGt) * tval;
        }
        float pos_exp = posAcc / (float)max(n_pos, 1);
        int valid = (k > 0 && n_pos > 0) ? 1 : 0;
        float denom = fmaxf(pos_exp + negExp, 1e-8f);
        float ratio = fminf(fmaxf(pos_exp / denom, 1e-8f), 1.0f);
        float loss = fminf(fmaxf(-logf(ratio), 0.f), 5.f);
        if (valid) { atomicAdd(&acc[0], loss); atomicAdd(&acc[1], 1.f); }
    }
}

// ---------------- K5: per-class boundary stats ----------------
__global__ __launch_bounds__(256) void k_class(
    const float* __restrict__ F, const int* __restrict__ labels,
    const float* __restrict__ scores, float* __restrict__ acc) {
    int c = blockIdx.x;
    int t = threadIdx.x;
    __shared__ int slab[B_];
    for (int r = t; r < B_; r += 256) slab[r] = labels[r];
    __shared__ float ssum; __shared__ int scnt;
    if (t == 0) { ssum = 0.f; scnt = 0; }
    __syncthreads();
    float s0 = 0.f, s1 = 0.f, q0 = 0.f, q1 = 0.f;
    float local_s = 0.f; int local_n = 0;
    for (int r = 0; r < B_; r++) {
        if (slab[r] == c) {
            const float* p = F + (size_t)r * D_;
            float v0 = p[t], v1 = p[t + 256];
            s0 += v0; s1 += v1; q0 += v0 * v0; q1 += v1 * v1;
            if (t == 0) { local_s += scores[r]; local_n++; }
        }
    }
    if (t == 0) { ssum = local_s; scnt = local_n; }
    __syncthreads();
    float fn = (float)scnt;
    float safe_n = fmaxf(fn, 1.f);
    float m0 = s0 / safe_n, m1 = s1 / safe_n;
    float dv = fmaxf(fn - 1.f, 1.f);
    float v0 = (q0 - fn * m0 * m0) / dv;
    float v1 = (q1 - fn * m1 * m1) / dv;
    __shared__ float red[256];
    red[t] = v0 + v1;
    __syncthreads();
    for (int s = 128; s > 0; s >>= 1) { if (t < s) red[t] += red[t + s]; __syncthreads(); }
    if (t == 0) {
        float var_mean = red[0] / 512.f;
        var_mean = fminf(fmaxf(var_mean, 1e-6f), 100.f);
        float target = 1.f / (1.f + expf(-var_mean));
        float mean_s = ssum / safe_n;
        float d = mean_s - target;
        float bl = fminf(d * d, 2.f);
        if (fn > 1.f) { atomicAdd(&acc[2], bl); atomicAdd(&acc[3], 1.f); }
    }
}

// ---------------- K6: PRD KL per row ----------------
__global__ __launch_bounds__(256) void k_prd(
    const float* __restrict__ F, const float* __restrict__ protos,
    const float* __restrict__ oldp, const int* __restrict__ lc,
    const float* __restrict__ inv_f, const float* __restrict__ inv_np,
    const float* __restrict__ inv_op, float* __restrict__ acc) {
    int row = blockIdx.x;
    int t = threadIdx.x;
    __shared__ float f[D_];
    __shared__ float so[L_], sn[L_];
    float invf = inv_f[row] * 5.0f;
    const float* p = F + (size_t)row * D_;
    f[t] = p[t]; f[t + 256] = p[t + 256];
    __syncthreads();
    int wave = t >> 6, lane = t & 63;
    for (int j = wave; j < 2 * L_; j += 4) {
        int idx = (j < L_) ? j : j - L_;
        const float* P = ((j < L_) ? oldp : protos) + (size_t)lc[idx] * D_;
        float inv = (j < L_) ? inv_op[idx] : inv_np[idx];
        float s = 0.f;
        for (int e = lane; e < D_; e += 64) s += f[e] * P[e];
#pragma unroll
        for (int off = 32; off > 0; off >>= 1) s += __shfl_down(s, off);
        if (lane == 0) {
            float v = fminf(fmaxf(s * invf * inv, -10.f), 10.f);
            if (j < L_) so[idx] = v; else sn[idx] = v;
        }
    }
    __syncthreads();
    if (t == 0) {
        float mo = -1e30f, mn = -1e30f;
        for (int i = 0; i < L_; i++) { mo = fmaxf(mo, so[i]); mn = fmaxf(mn, sn[i]); }
        float eo = 0.f, en = 0.f;
        for (int i = 0; i < L_; i++) { eo += __expf(so[i] - mo); en += __expf(sn[i] - mn); }
        float lo = logf(eo), ln_ = logf(en);
        float kl = 0.f;
        for (int i = 0; i < L_; i++) {
            float olp = so[i] - mo - lo;
            float nlp = sn[i] - mn - ln_;
            kl += __expf(olp) * (olp - nlp);
        }
        atomicAdd(&acc[4], kl);
    }
}

// ---------------- K7: combine ----------------
__global__ void k_final(const float* __restrict__ acc, float* __restrict__ out) {
    float hard = acc[0] / fmaxf(acc[1], 1.f);
    float boundary = acc[2] / fmaxf(acc[3], 1.f);
    float kl = fminf(fmaxf(acc[4] / (float)B_, 0.f), 5.f);
    out[0] = hard + 0.1f * boundary + 0.2f * kl;
}

extern "C" void kernel_launch(void* const* d_in, const int* in_sizes, int n_in,
                              void* d_out, int out_size, void* d_ws, size_t ws_size,
                              hipStream_t stream) {
    const float* feat   = (const float*)d_in[0];
    const float* buf    = (const float*)d_in[1];
    const float* protos = (const float*)d_in[2];
    const float* oldp   = (const float*)d_in[3];
    const float* W      = (const float*)d_in[4];
    const float* bb     = (const float*)d_in[5];
    const int* labels   = (const int*)d_in[6];
    const int* blab     = (const int*)d_in[7];
    const int* lc       = (const int*)d_in[8];
    float* out = (float*)d_out;

    char* wsb = (char*)d_ws;
    unsigned short* keyb = (unsigned short*)wsb;                        // 32 MiB
    __hip_bfloat16* fbf  = (__hip_bfloat16*)(wsb + 33554432);           // 1 MiB
    __hip_bfloat16* bbf  = (__hip_bfloat16*)(wsb + 34603008);           // 16 MiB
    unsigned long long* maskT = (unsigned long long*)(wsb + 51380224);  // 200 KiB
    float* inv_feat = (float*)(wsb + 51380224 + 204800);
    float* inv_np   = inv_feat + B_;
    float* inv_op   = inv_np + L_;
    float* scores   = inv_op + L_;
    int*   cnt_buf  = (int*)(scores + B_);
    float* acc      = (float*)(cnt_buf + 128);

    k_pre<<<C_ + B_ / 4, 256, 0, stream>>>(blab, feat, W, bb, maskT, cnt_buf, scores, acc);
    k_prep<<<B_ + M_ + 2 * L_, 256, 0, stream>>>(feat, buf, protos, oldp, lc,
                                                 fbf, bbf, inv_feat, inv_np, inv_op);
    dim3 g(M_ / TN, B_ / TM);
    k_gemm<<<g, 256, 0, stream>>>(fbf, bbf, keyb);
    k_select<<<B_, 256, 0, stream>>>(keyb, labels, maskT, cnt_buf, acc);
    k_class<<<C_, 256, 0, stream>>>(feat, labels, scores, acc);
    k_prd<<<B_, 256, 0, stream>>>(feat, protos, oldp, lc, inv_feat, inv_np, inv_op, acc);
    k_final<<<1, 1, 0, stream>>>(acc, out);
}

// Round 6
// 218.179 us; speedup vs baseline: 1.6612x; 1.2325x over previous
//
#include <hip/hip_runtime.h>
#include <hip/hip_bf16.h>
#include <math.h>

#define B_ 1024
#define M_ 16384
#define D_ 512
#define C_ 100
#define L_ 50

using short8  = __attribute__((ext_vector_type(8))) short;
using ushort8 = __attribute__((ext_vector_type(8))) unsigned short;
using f32x4   = __attribute__((ext_vector_type(4))) float;

__device__ inline void async16(const void* g, void* l) {
    __builtin_amdgcn_global_load_lds(
        (const __attribute__((address_space(1))) unsigned int*)g,
        (__attribute__((address_space(3))) unsigned int*)l, 16, 0, 0);
}

// ---------------- K_pre0: norms/bf16 + class bitmasks + counts + scores + acc zero ---
// blocks [0, B_+M_+2L_): norms + normalized bf16 (features/buffer) + proto inv norms
// blocks [P0, P0+C_): maskT[c][t] + cnt_buf[c]          (P0 = B_+M_+2L_)
// blocks [P0+C_, P0+C_+B_/4): scores = sigmoid(F@W+b); first scores-block zeroes acc
__global__ __launch_bounds__(256) void k_pre0(
    const float* __restrict__ feat, const float* __restrict__ buf,
    const float* __restrict__ protos, const float* __restrict__ oldp,
    const int* __restrict__ lc, const int* __restrict__ blab,
    const float* __restrict__ W, const float* __restrict__ bbias,
    __hip_bfloat16* __restrict__ fbf, __hip_bfloat16* __restrict__ bbf,
    float* __restrict__ inv_feat, float* __restrict__ inv_np, float* __restrict__ inv_op,
    unsigned long long* __restrict__ maskT, int* __restrict__ cnt_buf,
    float* __restrict__ scores, float* __restrict__ acc) {
    const int P0 = B_ + M_ + 2 * L_;
    int b = blockIdx.x, t = threadIdx.x;
    if (b < P0) {
        const float* src; int row;
        __hip_bfloat16* dst = nullptr; float* ndst = nullptr;
        if (b < B_)                { src = feat;   row = b;                 dst = fbf + (size_t)b * D_; ndst = &inv_feat[b]; }
        else if (b < B_ + M_)      { int j = b - B_;           src = buf;    row = j;     dst = bbf + (size_t)j * D_; }
        else if (b < B_ + M_ + L_) { int j = b - B_ - M_;      src = protos; row = lc[j]; ndst = &inv_np[j]; }
        else                       { int j = b - B_ - M_ - L_; src = oldp;   row = lc[j]; ndst = &inv_op[j]; }
        const float* p = src + (size_t)row * D_;
        float v0 = p[t], v1 = p[t + 256];
        float ss = v0 * v0 + v1 * v1;
#pragma unroll
        for (int m = 32; m; m >>= 1) ss += __shfl_xor(ss, m);
        __shared__ float w4[4];
        if ((t & 63) == 0) w4[t >> 6] = ss;
        __syncthreads();
        float inv = 1.f / fmaxf(sqrtf(w4[0] + w4[1] + w4[2] + w4[3]), 1e-12f);
        if (dst) { dst[t] = __float2bfloat16(v0 * inv); dst[t + 256] = __float2bfloat16(v1 * inv); }
        if (ndst && t == 0) *ndst = inv;
    } else if (b < P0 + C_) {
        int c2 = b - P0;
        unsigned long long m = 0;
#pragma unroll
        for (int q = 0; q < 8; q++) {
            int base = q * 2048 + t * 8;
            int4 l0 = *(const int4*)(blab + base);
            int4 l1 = *(const int4*)(blab + base + 4);
            unsigned by = 0;
            by |= (unsigned)(l0.x == c2) << 0; by |= (unsigned)(l0.y == c2) << 1;
            by |= (unsigned)(l0.z == c2) << 2; by |= (unsigned)(l0.w == c2) << 3;
            by |= (unsigned)(l1.x == c2) << 4; by |= (unsigned)(l1.y == c2) << 5;
            by |= (unsigned)(l1.z == c2) << 6; by |= (unsigned)(l1.w == c2) << 7;
            m |= ((unsigned long long)by) << (8 * q);
        }
        maskT[(size_t)c2 * 256 + t] = m;
        int c = __popcll(m);
#pragma unroll
        for (int o = 32; o; o >>= 1) c += __shfl_xor(c, o);
        __shared__ int iw4[4];
        if ((t & 63) == 0) iw4[t >> 6] = c;
        __syncthreads();
        if (t == 0) cnt_buf[c2] = iw4[0] + iw4[1] + iw4[2] + iw4[3];
    } else {
        int bb2 = b - P0 - C_;
        if (bb2 == 0 && t < 8) acc[t] = 0.f;
        int wave = t >> 6, lane = t & 63;
        int row = bb2 * 4 + wave;
        const float* p = feat + (size_t)row * D_;
        float s = 0.f;
        for (int e = lane; e < D_; e += 64) s += p[e] * W[e];
#pragma unroll
        for (int off = 32; off > 0; off >>= 1) s += __shfl_down(s, off);
        if (lane == 0) scores[row] = 1.f / (1.f + __expf(-(s + bbias[0])));
    }
}

// ---------------- K2: bf16 MFMA GEMM -> 16-bit sort keys (coalesced stores) ----
#define TM 128
#define TN 128
#define TK 32
#define CPITCH 136   // ushorts; 272 B pitch keeps 16B alignment for dwordx4
__global__ __launch_bounds__(256) void k_gemm(
    const __hip_bfloat16* __restrict__ A, const __hip_bfloat16* __restrict__ Bm,
    unsigned short* __restrict__ keys) {
    __shared__ unsigned short smem[TM * CPITCH];
    unsigned short* As = smem;
    unsigned short* Bs = smem + TM * TK;
    int t = threadIdx.x;
    int wave = t >> 6, lane = t & 63;
    int row0 = blockIdx.y * TM;
    int col0 = blockIdx.x * TN;
    int c0 = t, c1 = t + 256;
    const ushort* Ag0 = (const ushort*)A + (size_t)(row0 + (c0 >> 2)) * D_ + (c0 & 3) * 8;
    const ushort* Ag1 = (const ushort*)A + (size_t)(row0 + (c1 >> 2)) * D_ + (c1 & 3) * 8;
    const ushort* Bg0 = (const ushort*)Bm + (size_t)(col0 + (c0 >> 2)) * D_ + (c0 & 3) * 8;
    const ushort* Bg1 = (const ushort*)Bm + (size_t)(col0 + (c1 >> 2)) * D_ + (c1 & 3) * 8;
    unsigned short* As0 = &As[c0 * 8]; unsigned short* As1 = &As[c1 * 8];
    unsigned short* Bs0 = &Bs[c0 * 8]; unsigned short* Bs1 = &Bs[c1 * 8];
    int wm = (wave & 1) * 64, wn = (wave >> 1) * 64;
    f32x4 acc[4][4];
#pragma unroll
    for (int i = 0; i < 4; i++)
#pragma unroll
        for (int j = 0; j < 4; j++) acc[i][j] = {0.f, 0.f, 0.f, 0.f};
    int fr = lane & 15, fk = (lane >> 4) * 8;
    for (int k0 = 0; k0 < D_; k0 += TK) {
        async16(Ag0 + k0, As0);
        async16(Ag1 + k0, As1);
        async16(Bg0 + k0, Bs0);
        async16(Bg1 + k0, Bs1);
        __syncthreads();
        short8 af[4], bf2[4];
#pragma unroll
        for (int i = 0; i < 4; i++)
            af[i] = *(const short8*)&As[(wm + i * 16 + fr) * TK + fk];
#pragma unroll
        for (int j = 0; j < 4; j++)
            bf2[j] = *(const short8*)&Bs[(wn + j * 16 + fr) * TK + fk];
#pragma unroll
        for (int i = 0; i < 4; i++)
#pragma unroll
            for (int j = 0; j < 4; j++)
                acc[i][j] = __builtin_amdgcn_mfma_f32_16x16x32_bf16(af[i], bf2[j], acc[i][j], 0, 0, 0);
        __syncthreads();
    }
    int quad = lane >> 4, cpos = lane & 15;
#pragma unroll
    for (int i = 0; i < 4; i++)
#pragma unroll
        for (int j = 0; j < 4; j++)
#pragma unroll
            for (int r = 0; r < 4; r++) {
                int lr2 = wm + i * 16 + quad * 4 + r;
                int lc2 = wn + j * 16 + cpos;
                float v = fminf(fmaxf(acc[i][j][r] * 5.0f, -10.f), 10.f);
                unsigned u = __float_as_uint(v);
                unsigned bits = (u + 0x7FFFu + ((u >> 16) & 1u)) >> 16;   // RNE bf16
                unsigned key = (bits & 0x8000u) ? (~bits & 0xFFFFu) : (bits | 0x8000u);
                smem[lr2 * CPITCH + lc2] = (unsigned short)key;
            }
    __syncthreads();
    int lr3 = t >> 4, lc3 = (t & 15) * 8;
#pragma unroll
    for (int p = 0; p < 8; p++) {
        int row = p * 16 + lr3;
        uint4 kv = *(const uint4*)&smem[row * CPITCH + lc3];
        *(uint4*)&keys[(size_t)(row0 + row) * M_ + col0 + lc3] = kv;
    }
}

// ---------------- K3: per-row exact top-k via bisection on packed keys ----------
__global__ __launch_bounds__(256) void k_select(
    const unsigned short* __restrict__ keys, const int* __restrict__ labels,
    const unsigned long long* __restrict__ maskT, const int* __restrict__ cnt_buf,
    float* __restrict__ acc) {
    int row = blockIdx.x;
    int t = threadIdx.x;
    int wave = t >> 6;
    int lab = labels[row];
    unsigned long long pm = maskT[(size_t)lab * 256 + t];
    const unsigned short* kr = keys + (size_t)row * M_ + t * 8;

    unsigned kp[32];
    float pp = 0.f;
#pragma unroll
    for (int q = 0; q < 8; q++) {
        uint4 v = *(const uint4*)(kr + q * 2048);
        unsigned pb = (unsigned)(pm >> (8 * q)) & 0xFFu;
        unsigned w[4] = {v.x, v.y, v.z, v.w};
        if (pb) {
#pragma unroll
            for (int h = 0; h < 4; h++) {
                if (pb & (1u << (2 * h))) {
                    unsigned key = w[h] & 0xFFFFu;
                    unsigned bits = (key & 0x8000u) ? (key ^ 0x8000u) : (~key & 0xFFFFu);
                    pp += __expf(__uint_as_float(bits << 16));
                    w[h] &= 0xFFFF0000u;
                }
                if (pb & (2u << (2 * h))) {
                    unsigned key = w[h] >> 16;
                    unsigned bits = (key & 0x8000u) ? (key ^ 0x8000u) : (~key & 0xFFFFu);
                    pp += __expf(__uint_as_float(bits << 16));
                    w[h] &= 0x0000FFFFu;
                }
            }
        }
        kp[q * 4 + 0] = w[0]; kp[q * 4 + 1] = w[1];
        kp[q * 4 + 2] = w[2]; kp[q * 4 + 3] = w[3];
    }

    int n_pos = cnt_buf[lab];
    int k = (int)(0.7f * (float)(M_ - n_pos));   // fp32-mul + trunc matches reference

    __shared__ int warr[16][4];
    unsigned cur = 0;
    for (int r = 15; r >= 0; r--) {
        int T = (int)(cur | (1u << r));
        int neg = 0;
#pragma unroll
        for (int q = 0; q < 32; q++) {
            neg += ((int)(kp[q] & 0xFFFFu) - T) >> 31;
            neg += ((int)(kp[q] >> 16) - T) >> 31;
        }
        int cnt = 64 + neg;
#pragma unroll
        for (int o = 32; o; o >>= 1) cnt += __shfl_xor(cnt, o);
        if ((t & 63) == 0) warr[15 - r][wave] = cnt;
        __syncthreads();
        int tot = warr[15 - r][0] + warr[15 - r][1] + warr[15 - r][2] + warr[15 - r][3];
        if (tot >= k) cur = (unsigned)T;
    }

    int cgt = 0; float sgt = 0.f;
#pragma unroll
    for (int q = 0; q < 32; q++) {
#pragma unroll
        for (int h = 0; h < 2; h++) {
            unsigned key = h ? (kp[q] >> 16) : (kp[q] & 0xFFFFu);
            if (key > cur) {
                cgt++;
                unsigned bits = (key & 0x8000u) ? (key ^ 0x8000u) : (~key & 0xFFFFu);
                sgt += __expf(__uint_as_float(bits << 16));
            }
        }
    }
#pragma unroll
    for (int o = 32; o; o >>= 1) {
        pp  += __shfl_xor(pp, o);
        sgt += __shfl_xor(sgt, o);
        cgt += __shfl_xor(cgt, o);
    }
    __shared__ float rP[4], rS[4]; __shared__ int rC[4];
    if ((t & 63) == 0) { rP[wave] = pp; rS[wave] = sgt; rC[wave] = cgt; }
    __syncthreads();
    if (t == 0) {
        float posAcc = rP[0] + rP[1] + rP[2] + rP[3];
        float sumGt  = rS[0] + rS[1] + rS[2] + rS[3];
        int   cntGt  = rC[0] + rC[1] + rC[2] + rC[3];
        float negExp = 0.f;
        if (k > 0) {
            unsigned bits = (cur & 0x8000u) ? (cur ^ 0x8000u) : (~cur & 0xFFFFu);
            float tval = __expf(__uint_as_float(bits << 16));
            negExp = sumGt + (float)(k - cntGt) * tval;
        }
        float pos_exp = posAcc / (float)max(n_pos, 1);
        int valid = (k > 0 && n_pos > 0) ? 1 : 0;
        float denom = fmaxf(pos_exp + negExp, 1e-8f);
        float ratio = fminf(fmaxf(pos_exp / denom, 1e-8f), 1.0f);
        float loss = fminf(fmaxf(-logf(ratio), 0.f), 5.f);
        if (valid) { atomicAdd(&acc[0], loss); atomicAdd(&acc[1], 1.f); }
    }
}

// ---------------- K_tail: class boundary stats (compacted) + PRD KL ----------------
// blocks [0,C_): boundary stats for class b via row-list compaction
// blocks [C_, C_+B_): PRD KL for feature row b-C_
__global__ __launch_bounds__(256) void k_tail(
    const float* __restrict__ F, const int* __restrict__ labels,
    const float* __restrict__ scores,
    const float* __restrict__ protos, const float* __restrict__ oldp,
    const int* __restrict__ lc, const float* __restrict__ inv_f,
    const float* __restrict__ inv_np, const float* __restrict__ inv_op,
    float* __restrict__ acc) {
    int b = blockIdx.x, t = threadIdx.x;
    if (b < C_) {
        int c = b;
        __shared__ int list[B_];
        __shared__ int cnt;
        if (t == 0) cnt = 0;
        __syncthreads();
        for (int i = t; i < B_; i += 256)
            if (labels[i] == c) { int pos = atomicAdd(&cnt, 1); list[pos] = i; }
        __syncthreads();
        int n = cnt;
        float s0 = 0.f, s1 = 0.f, q0 = 0.f, q1 = 0.f, sc = 0.f;
        for (int j = 0; j < n; j++) {
            int r = list[j];
            const float* p = F + (size_t)r * D_;
            float v0 = p[t], v1 = p[t + 256];
            s0 += v0; s1 += v1; q0 += v0 * v0; q1 += v1 * v1;
        }
        for (int j = t; j < n; j += 256) sc += scores[list[j]];
        float fn = (float)n;
        float safe_n = fmaxf(fn, 1.f);
        float m0 = s0 / safe_n, m1 = s1 / safe_n;
        float dv = fmaxf(fn - 1.f, 1.f);
        float v0 = (q0 - fn * m0 * m0) / dv;
        float v1 = (q1 - fn * m1 * m1) / dv;
        float rv = v0 + v1;
#pragma unroll
        for (int o = 32; o; o >>= 1) { rv += __shfl_xor(rv, o); sc += __shfl_xor(sc, o); }
        __shared__ float wv[4], wsc[4];
        if ((t & 63) == 0) { wv[t >> 6] = rv; wsc[t >> 6] = sc; }
        __syncthreads();
        if (t == 0) {
            float var_mean = (wv[0] + wv[1] + wv[2] + wv[3]) / 512.f;
            var_mean = fminf(fmaxf(var_mean, 1e-6f), 100.f);
            float target = 1.f / (1.f + expf(-var_mean));
            float mean_s = (wsc[0] + wsc[1] + wsc[2] + wsc[3]) / safe_n;
            float d = mean_s - target;
            float bl = fminf(d * d, 2.f);
            if (fn > 1.f) { atomicAdd(&acc[2], bl); atomicAdd(&acc[3], 1.f); }
        }
    } else {
        int row = b - C_;
        __shared__ float f[D_];
        __shared__ float so[L_], sn[L_];
        float invf = inv_f[row] * 5.0f;
        const float* p = F + (size_t)row * D_;
        f[t] = p[t]; f[t + 256] = p[t + 256];
        __syncthreads();
        int wave = t >> 6, lane = t & 63;
        for (int j = wave; j < 2 * L_; j += 4) {
            int idx = (j < L_) ? j : j - L_;
            const float* P = ((j < L_) ? oldp : protos) + (size_t)lc[idx] * D_;
            float inv = (j < L_) ? inv_op[idx] : inv_np[idx];
            float s = 0.f;
            for (int e = lane; e < D_; e += 64) s += f[e] * P[e];
#pragma unroll
            for (int off = 32; off > 0; off >>= 1) s += __shfl_down(s, off);
            if (lane == 0) {
                float v = fminf(fmaxf(s * invf * inv, -10.f), 10.f);
                if (j < L_) so[idx] = v; else sn[idx] = v;
            }
        }
        __syncthreads();
        if (t == 0) {
            float mo = -1e30f, mn = -1e30f;
            for (int i = 0; i < L_; i++) { mo = fmaxf(mo, so[i]); mn = fmaxf(mn, sn[i]); }
            float eo = 0.f, en = 0.f;
            for (int i = 0; i < L_; i++) { eo += __expf(so[i] - mo); en += __expf(sn[i] - mn); }
            float lo = logf(eo), ln_ = logf(en);
            float kl = 0.f;
            for (int i = 0; i < L_; i++) {
                float olp = so[i] - mo - lo;
                float nlp = sn[i] - mn - ln_;
                kl += __expf(olp) * (olp - nlp);
            }
            atomicAdd(&acc[4], kl);
        }
    }
}

// ---------------- K_final: combine ----------------
__global__ void k_final(const float* __restrict__ acc, float* __restrict__ out) {
    float hard = acc[0] / fmaxf(acc[1], 1.f);
    float boundary = acc[2] / fmaxf(acc[3], 1.f);
    float kl = fminf(fmaxf(acc[4] / (float)B_, 0.f), 5.f);
    out[0] = hard + 0.1f * boundary + 0.2f * kl;
}

extern "C" void kernel_launch(void* const* d_in, const int* in_sizes, int n_in,
                              void* d_out, int out_size, void* d_ws, size_t ws_size,
                              hipStream_t stream) {
    const float* feat   = (const float*)d_in[0];
    const float* buf    = (const float*)d_in[1];
    const float* protos = (const float*)d_in[2];
    const float* oldp   = (const float*)d_in[3];
    const float* W      = (const float*)d_in[4];
    const float* bb     = (const float*)d_in[5];
    const int* labels   = (const int*)d_in[6];
    const int* blab     = (const int*)d_in[7];
    const int* lc       = (const int*)d_in[8];
    float* out = (float*)d_out;

    char* wsb = (char*)d_ws;
    unsigned short* keyb = (unsigned short*)wsb;                        // 32 MiB
    __hip_bfloat16* fbf  = (__hip_bfloat16*)(wsb + 33554432);           // 1 MiB
    __hip_bfloat16* bbf  = (__hip_bfloat16*)(wsb + 34603008);           // 16 MiB
    unsigned long long* maskT = (unsigned long long*)(wsb + 51380224);  // 200 KiB
    float* inv_feat = (float*)(wsb + 51380224 + 204800);
    float* inv_np   = inv_feat + B_;
    float* inv_op   = inv_np + L_;
    float* scores   = inv_op + L_;
    int*   cnt_buf  = (int*)(scores + B_);
    float* acc      = (float*)(cnt_buf + 128);

    const int P0 = B_ + M_ + 2 * L_;
    k_pre0<<<P0 + C_ + B_ / 4, 256, 0, stream>>>(feat, buf, protos, oldp, lc, blab, W, bb,
                                                 fbf, bbf, inv_feat, inv_np, inv_op,
                                                 maskT, cnt_buf, scores, acc);
    dim3 g(M_ / TN, B_ / TM);
    k_gemm<<<g, 256, 0, stream>>>(fbf, bbf, keyb);
    k_select<<<B_, 256, 0, stream>>>(keyb, labels, maskT, cnt_buf, acc);
    k_tail<<<C_ + B_, 256, 0, stream>>>(feat, labels, scores, protos, oldp, lc,
                                        inv_feat, inv_np, inv_op, acc);
    k_final<<<1, 1, 0, stream>>>(acc, out);
}